// Round 3
// baseline (1291.683 us; speedup 1.0000x reference)
//
#include <hip/hip_runtime.h>

// Correlation: out[b,(di+4)*9+(dj+4),i,j] = (1/128) * sum_c f1[b,c,i,j]*f2[b,c,i+di,j+dj]
// B=8 C=128 H=128 W=256, di,dj in [-4,4], f2 zero-padded.
//
// v6: 3 di PER WAVE. v5 post-mortem: with one di per wave, every block issued
// 9x redundant f1 loads (2.3MB/block through TA), FMA:load ratio was fixed at
// 18/KB, and 9-wave workgroups quantized occupancy to ~1 block/CU (25%).
// Both v3 (LDS) and v5 (DPP) hit the same 226-235us wall -> the decomposition,
// not the inner loop, was the limiter.
// Now: block = 3 waves, one (b,i0) per block. Wave g handles di in
// {3g-4,3g-3,3g-2}: per channel it loads f1 once + 3 f2 rows (4 loads,
// 108 FMAs -> 27 FMA/KB, f1 redundancy 9x->3x, block load bytes 1.54MB).
// acc[3][9][4]=108 VGPRs, ping-pong 1-chunk-ahead prefetch (no register
// copies for the compiler to elide), __launch_bounds__(192,3) -> 170-VGPR
// budget so the prefetch SURVIVES (v3/v5 failure mode: VGPR 48/56 = sunk).
// DPP wave_shr/shl halo (bound_ctrl:0 zero-fill = image column padding,
// verified v4/v5). XCD-chunked swizzle kept (verified: FETCH 143MB).

#define CT 128
#define HH 128
#define WW 256
#define NK 81
#define HW ((size_t)HH * WW)

// lane l <- lane l-1 ; lane 0 <- 0   (DPP wave_shr:1, bound_ctrl:0)
__device__ __forceinline__ float halo_left(float x) {
    return __int_as_float(__builtin_amdgcn_update_dpp(
        0, __float_as_int(x), 0x138, 0xF, 0xF, true));
}
// lane l <- lane l+1 ; lane 63 <- 0  (DPP wave_shl:1, bound_ctrl:0)
__device__ __forceinline__ float halo_right(float x) {
    return __int_as_float(__builtin_amdgcn_update_dpp(
        0, __float_as_int(x), 0x130, 0xF, 0xF, true));
}

__global__ __launch_bounds__(192, 3)
void corr_kernel(const float* __restrict__ f1, const float* __restrict__ f2,
                 float* __restrict__ out) {
    const int l  = threadIdx.x & 63;       // lane: cols 4l..4l+3
    const int g  = threadIdx.x >> 6;       // 0..2: di group
    const int p  = blockIdx.x;
    const int L  = ((p & 7) << 7) | (p >> 3);  // XCD-chunked: XCD = batch
    const int b  = L >> 7;
    const int i0 = L & 127;

    const float* p1 = f1 + ((size_t)b * CT * HH + i0) * WW + 4 * l;

    // this wave's 3 f2 rows: R[j] = i0 - 4 + 3g + j
    bool rv[3];
    const float* p2r[3];
#pragma unroll
    for (int j = 0; j < 3; ++j) {
        const int R = i0 - 4 + 3 * g + j;
        rv[j] = ((unsigned)R < (unsigned)HH);
        p2r[j] = f2 + ((size_t)b * CT * HH + (rv[j] ? R : 0)) * WW + 4 * l;
    }

    float acc[3][9][4];
#pragma unroll
    for (int j = 0; j < 3; ++j)
#pragma unroll
        for (int d = 0; d < 9; ++d)
#pragma unroll
            for (int t = 0; t < 4; ++t) acc[j][d][t] = 0.f;

    const float4 z4 = make_float4(0.f, 0.f, 0.f, 0.f);
    auto LOAD = [&](int q, float4& A, float4 B[3]) {
        A = *(const float4*)(p1 + (size_t)q * HW);
#pragma unroll
        for (int j = 0; j < 3; ++j)
            B[j] = rv[j] ? *(const float4*)(p2r[j] + (size_t)q * HW) : z4;
    };

    auto COMPUTE = [&](const float4& A, const float4 B[3]) {
        const float fv[4] = {A.x, A.y, A.z, A.w};
#pragma unroll
        for (int j = 0; j < 3; ++j) {
            const float4& r = B[j];
            float w[12];                    // image cols 4l-4 .. 4l+7
            w[0]  = halo_left(r.x);  w[1]  = halo_left(r.y);
            w[2]  = halo_left(r.z);  w[3]  = halo_left(r.w);
            w[4]  = r.x;             w[5]  = r.y;
            w[6]  = r.z;             w[7]  = r.w;
            w[8]  = halo_right(r.x); w[9]  = halo_right(r.y);
            w[10] = halo_right(r.z); w[11] = halo_right(r.w);
#pragma unroll
            for (int d = 0; d < 9; ++d)
#pragma unroll
                for (int t = 0; t < 4; ++t)
                    acc[j][d][t] += fv[t] * w[t + d];
        }
    };

    // ping-pong software pipeline, one channel ahead; no inter-buffer copies
    float4 A0, B0[3], A1, B1[3];
    LOAD(0, A0, B0);
    for (int q = 0; q < CT; q += 2) {
        LOAD(q + 1, A1, B1);                    // prefetch odd channel
        __builtin_amdgcn_sched_barrier(0);
        COMPUTE(A0, B0);
        if (q + 2 < CT) LOAD(q + 2, A0, B0);    // prefetch next even channel
        __builtin_amdgcn_sched_barrier(0);
        COMPUTE(A1, B1);
    }

    const float s = 1.0f / 128.0f;
#pragma unroll
    for (int j = 0; j < 3; ++j) {
        const int k = (3 * g + j) * 9;          // base kernel index for this row
#pragma unroll
        for (int d = 0; d < 9; ++d) {
            float* op = out + ((size_t)(b * NK + k + d) * HH + i0) * WW + 4 * l;
            *(float4*)op = make_float4(acc[j][d][0] * s, acc[j][d][1] * s,
                                       acc[j][d][2] * s, acc[j][d][3] * s);
        }
    }
}

extern "C" void kernel_launch(void* const* d_in, const int* in_sizes, int n_in,
                              void* d_out, int out_size, void* d_ws, size_t ws_size,
                              hipStream_t stream) {
    const float* f1 = (const float*)d_in[0];
    const float* f2 = (const float*)d_in[1];
    float* out = (float*)d_out;
    dim3 grid(1024);       // one block per (b, i0); swizzled so XCD = batch
    dim3 block(192);       // 3 waves, 3 di each; no LDS, no barriers
    hipLaunchKernelGGL(corr_kernel, grid, block, 0, stream, f1, f2, out);
}

// Round 4
// 492.242 us; speedup vs baseline: 2.6241x; 2.6241x over previous
//
#include <hip/hip_runtime.h>

// Correlation: out[b,(di+4)*9+(dj+4),i,j] = (1/128) * sum_c f1[b,c,i,j]*f2[b,c,i+di,j+dj]
// B=8 C=128 H=128 W=256, di,dj in [-4,4], f2 zero-padded.
//
// v7: v6 post-mortem: WRITE_SIZE 83MB->2.44GB + VGPR=84 = the acc[3][9][4] was
// SPILLED TO SCRATCH (ping-pong peak live set ~180 regs > 170 cap; float4[3]
// lambda params took addresses -> allocator dumped acc to memory). The 3-di-
// per-wave idea was never actually tested.
// v7 fixes register pressure BY CONSTRUCTION:
//  - no ping-pong: per 2-channel chunk, 8 batched loads into NAMED float4s ->
//    sched_barrier(0) -> 312 VALU ops. Peak live ~155 regs < 170 cap.
//  - no arrays through lambdas/calls: macros with literal indices; only acc
//    (static idx, never escapes) and transient w[12] (v5-proven SROA pattern).
//  - structure kept from v6: 3 waves/block, wave g = di in {3g-4..3g-2},
//    f1 loaded once per channel (reuse x3), XCD-chunked swizzle (FETCH 143MB
//    proven), DPP wave_shr/shl halo = free column zero-padding (proven v4/v5).
// Checks for the counters: WRITE back to ~83MB, VGPR 140-168, VALUBusy 55-75%.

#define CT 128
#define HH 128
#define WW 256
#define NK 81
#define HW ((size_t)HH * WW)

// lane l <- lane l-1 ; lane 0 <- 0   (DPP wave_shr:1, bound_ctrl:0)
__device__ __forceinline__ float halo_left(float x) {
    return __int_as_float(__builtin_amdgcn_update_dpp(
        0, __float_as_int(x), 0x138, 0xF, 0xF, true));
}
// lane l <- lane l+1 ; lane 63 <- 0  (DPP wave_shl:1, bound_ctrl:0)
__device__ __forceinline__ float halo_right(float x) {
    return __int_as_float(__builtin_amdgcn_update_dpp(
        0, __float_as_int(x), 0x130, 0xF, 0xF, true));
}

// 8 batched loads for 2 channels (all named vars; selects for edge rows)
#define LOAD_CH(q, A, B0, B1, B2)                                       \
    A  = *(const float4*)(p1 + (size_t)(q) * HW);                       \
    B0 = rv0 ? *(const float4*)(p2a + (size_t)(q) * HW) : z4;           \
    B1 = rv1 ? *(const float4*)(p2b + (size_t)(q) * HW) : z4;           \
    B2 = rv2 ? *(const float4*)(p2c + (size_t)(q) * HW) : z4;

// one f2 row's 9-dj contribution; j is a LITERAL, acc never escapes
#define COMP_ROW(j, r)                                                  \
    {                                                                   \
        float w[12]; /* image cols 4l-4 .. 4l+7 */                      \
        w[0] = halo_left(r.x);  w[1] = halo_left(r.y);                  \
        w[2] = halo_left(r.z);  w[3] = halo_left(r.w);                  \
        w[4] = r.x; w[5] = r.y; w[6] = r.z; w[7] = r.w;                 \
        w[8] = halo_right(r.x);  w[9] = halo_right(r.y);                \
        w[10] = halo_right(r.z); w[11] = halo_right(r.w);               \
        _Pragma("unroll")                                               \
        for (int d = 0; d < 9; ++d) {                                   \
            acc[j][d][0] += fv0 * w[d];                                 \
            acc[j][d][1] += fv1 * w[d + 1];                             \
            acc[j][d][2] += fv2 * w[d + 2];                             \
            acc[j][d][3] += fv3 * w[d + 3];                             \
        }                                                               \
    }

#define COMP_CH(A, Bx, By, Bz)                                          \
    {                                                                   \
        const float fv0 = A.x, fv1 = A.y, fv2 = A.z, fv3 = A.w;         \
        COMP_ROW(0, Bx)                                                 \
        COMP_ROW(1, By)                                                 \
        COMP_ROW(2, Bz)                                                 \
    }

__global__ __launch_bounds__(192, 3)
void corr_kernel(const float* __restrict__ f1, const float* __restrict__ f2,
                 float* __restrict__ out) {
    const int l  = threadIdx.x & 63;       // lane: cols 4l..4l+3
    const int g  = threadIdx.x >> 6;       // 0..2: di group
    const int p  = blockIdx.x;
    const int L  = ((p & 7) << 7) | (p >> 3);  // XCD-chunked: XCD = batch
    const int b  = L >> 7;
    const int i0 = L & 127;

    const int  R0  = i0 - 4 + 3 * g;       // this wave's 3 f2 rows: R0..R0+2
    const bool rv0 = (unsigned)(R0)     < (unsigned)HH;
    const bool rv1 = (unsigned)(R0 + 1) < (unsigned)HH;
    const bool rv2 = (unsigned)(R0 + 2) < (unsigned)HH;

    const float* p1  = f1 + ((size_t)b * CT * HH + i0) * WW + 4 * l;
    const float* p2a = f2 + ((size_t)b * CT * HH + (rv0 ? R0     : 0)) * WW + 4 * l;
    const float* p2b = f2 + ((size_t)b * CT * HH + (rv1 ? R0 + 1 : 0)) * WW + 4 * l;
    const float* p2c = f2 + ((size_t)b * CT * HH + (rv2 ? R0 + 2 : 0)) * WW + 4 * l;

    const float4 z4 = make_float4(0.f, 0.f, 0.f, 0.f);

    float acc[3][9][4];
#pragma unroll
    for (int j = 0; j < 3; ++j)
#pragma unroll
        for (int d = 0; d < 9; ++d)
#pragma unroll
            for (int t = 0; t < 4; ++t) acc[j][d][t] = 0.f;

    // 64 chunks of 2 channels: 8 clustered loads, one wait, 312 VALU ops
    for (int q = 0; q < CT; q += 2) {
        float4 Aa, B0a, B1a, B2a, Ab, B0b, B1b, B2b;
        LOAD_CH(q,     Aa, B0a, B1a, B2a)
        LOAD_CH(q + 1, Ab, B0b, B1b, B2b)
        __builtin_amdgcn_sched_barrier(0);   // all 8 issued before any use
        COMP_CH(Aa, B0a, B1a, B2a)
        COMP_CH(Ab, B0b, B1b, B2b)
    }

    const float s = 1.0f / 128.0f;
#pragma unroll
    for (int j = 0; j < 3; ++j) {
        const int k = (3 * g + j) * 9;
#pragma unroll
        for (int d = 0; d < 9; ++d) {
            float* op = out + ((size_t)(b * NK + k + d) * HH + i0) * WW + 4 * l;
            *(float4*)op = make_float4(acc[j][d][0] * s, acc[j][d][1] * s,
                                       acc[j][d][2] * s, acc[j][d][3] * s);
        }
    }
}

extern "C" void kernel_launch(void* const* d_in, const int* in_sizes, int n_in,
                              void* d_out, int out_size, void* d_ws, size_t ws_size,
                              hipStream_t stream) {
    const float* f1 = (const float*)d_in[0];
    const float* f2 = (const float*)d_in[1];
    float* out = (float*)d_out;
    dim3 grid(1024);       // one block per (b, i0); swizzled so XCD = batch
    dim3 block(192);       // 3 waves, 3 di each; no LDS, no barriers
    hipLaunchKernelGGL(corr_kernel, grid, block, 0, stream, f1, f2, out);
}

// Round 5
// 343.297 us; speedup vs baseline: 3.7626x; 1.4339x over previous
//
#include <hip/hip_runtime.h>

// Correlation: out[b,(di+4)*9+(dj+4),i,j] = (1/128) * sum_c f1[b,c,i,j]*f2[b,c,i+di,j+dj]
// B=8 C=128 H=128 W=256, di,dj in [-4,4], f2 zero-padded.
//
// v8: ASYNC LDS PIPELINE (T3/T4). v3/v5/v7 post-mortems: source-level register
// prefetch fails three ways (sunk / paired / AGPR-squeezed at VGPR=84); every
// variant stalls at VALUBusy 26-30% with ~10% per-wave duty cycle. Fix: staging
// that needs NO registers. Each wave owns a private 3-slot LDS ring; per
// channel-iteration: stage ch q+3 via 4x global_load_lds (width 16: f1 + 3 f2
// rows, 1KB each, LDS dest = wave-uniform row base + lane*16), wait
// s_waitcnt vmcnt(8) (stage q done; q+1,q+2 IN FLIGHT - never drain to 0),
// ds_read ch q, lgkmcnt(0), re-stage into freed slot, compute. Load->use
// distance = 3 iters (~2700 cy) >> HBM 900. Uniform 4 loads/stage for exact
// vmcnt bookkeeping: invalid edge rows and tail stages go to a trash row
// (sources clamped in-bounds); real edge rows pre-zeroed once, never staged.
// Kept from v7: 3 waves/block, 3 di/wave (f1 reuse x3), XCD-chunked swizzle,
// DPP wave_shr/shl halo (zero-fill = column padding). No barriers anywhere.
// LDS 37.9KB -> 4 blocks/CU = 12 waves/CU; acc[3][9][4] stays in VGPRs (<=170).

#define CT 128
#define HH 128
#define WW 256
#define NK 81
#define HW ((size_t)HH * WW)
#define NSLOT 3

// lane l <- lane l-1 ; lane 0 <- 0   (DPP wave_shr:1, bound_ctrl:0)
__device__ __forceinline__ float halo_left(float x) {
    return __int_as_float(__builtin_amdgcn_update_dpp(
        0, __float_as_int(x), 0x138, 0xF, 0xF, true));
}
// lane l <- lane l+1 ; lane 63 <- 0  (DPP wave_shl:1, bound_ctrl:0)
__device__ __forceinline__ float halo_right(float x) {
    return __int_as_float(__builtin_amdgcn_update_dpp(
        0, __float_as_int(x), 0x130, 0xF, 0xF, true));
}

typedef const __attribute__((address_space(1))) void* gas_ptr;
typedef __attribute__((address_space(3))) void* las_ptr;

// one row: lane l's 16B from global (per-lane addr) -> LDS base + 16*l (uniform base)
#define STG(gp, dst) \
    __builtin_amdgcn_global_load_lds((gas_ptr)(gp), (las_ptr)(dst), 16, 0, 0);

// uniform 4-load stage of channel qq into slot ss; 'real' false -> all to trash
#define STAGE(qq, ss, real)                                                   \
    {                                                                         \
        STG(p1 + (size_t)(qq) * HW,                                           \
            (real) ? (void*)&lds[g][ss][0][0] : (void*)&trash[0])             \
        STG(p2a + (size_t)(qq) * HW,                                          \
            ((real) && rv0) ? (void*)&lds[g][ss][1][0] : (void*)&trash[0])    \
        STG(p2b + (size_t)(qq) * HW,                                          \
            ((real) && rv1) ? (void*)&lds[g][ss][2][0] : (void*)&trash[0])    \
        STG(p2c + (size_t)(qq) * HW,                                          \
            ((real) && rv2) ? (void*)&lds[g][ss][3][0] : (void*)&trash[0])    \
    }

// one f2 row's 9-dj contribution; j literal, acc never escapes
#define COMP_ROW(j, r)                                                  \
    {                                                                   \
        float w[12]; /* image cols 4l-4 .. 4l+7 */                      \
        w[0] = halo_left(r.x);  w[1] = halo_left(r.y);                  \
        w[2] = halo_left(r.z);  w[3] = halo_left(r.w);                  \
        w[4] = r.x; w[5] = r.y; w[6] = r.z; w[7] = r.w;                 \
        w[8] = halo_right(r.x);  w[9] = halo_right(r.y);                \
        w[10] = halo_right(r.z); w[11] = halo_right(r.w);               \
        _Pragma("unroll")                                               \
        for (int d = 0; d < 9; ++d) {                                   \
            acc[j][d][0] += fv0 * w[d];                                 \
            acc[j][d][1] += fv1 * w[d + 1];                             \
            acc[j][d][2] += fv2 * w[d + 2];                             \
            acc[j][d][3] += fv3 * w[d + 3];                             \
        }                                                               \
    }

__global__ __launch_bounds__(192, 3)
void corr_kernel(const float* __restrict__ f1, const float* __restrict__ f2,
                 float* __restrict__ out) {
    // wave-private: lds[g] only ever touched by wave g -> NO barriers
    __shared__ __align__(16) float lds[3][NSLOT][4][WW];  // 36,864 B
    __shared__ __align__(16) float trash[WW];             //  1,024 B (write-only)

    const int l  = threadIdx.x & 63;       // lane: cols 4l..4l+3
    const int g  = threadIdx.x >> 6;       // 0..2: di group
    const int p  = blockIdx.x;
    const int L  = ((p & 7) << 7) | (p >> 3);  // XCD-chunked: XCD = batch
    const int b  = L >> 7;
    const int i0 = L & 127;

    const int  R0  = i0 - 4 + 3 * g;       // this wave's 3 f2 rows: R0..R0+2
    const bool rv0 = (unsigned)(R0)     < (unsigned)HH;
    const bool rv1 = (unsigned)(R0 + 1) < (unsigned)HH;
    const bool rv2 = (unsigned)(R0 + 2) < (unsigned)HH;

    const float* p1  = f1 + ((size_t)b * CT * HH + i0) * WW + 4 * l;
    const float* p2a = f2 + ((size_t)b * CT * HH + (rv0 ? R0     : 0)) * WW + 4 * l;
    const float* p2b = f2 + ((size_t)b * CT * HH + (rv1 ? R0 + 1 : 0)) * WW + 4 * l;
    const float* p2c = f2 + ((size_t)b * CT * HH + (rv2 ? R0 + 2 : 0)) * WW + 4 * l;

    // pre-zero invalid f2 rows (all slots) once; they are never staged over.
    const float4 z4 = make_float4(0.f, 0.f, 0.f, 0.f);
    if (!rv0)
        for (int ss = 0; ss < NSLOT; ++ss) *(float4*)&lds[g][ss][1][4 * l] = z4;
    if (!rv1)
        for (int ss = 0; ss < NSLOT; ++ss) *(float4*)&lds[g][ss][2][4 * l] = z4;
    if (!rv2)
        for (int ss = 0; ss < NSLOT; ++ss) *(float4*)&lds[g][ss][3][4 * l] = z4;

    float acc[3][9][4];
#pragma unroll
    for (int j = 0; j < 3; ++j)
#pragma unroll
        for (int d = 0; d < 9; ++d)
#pragma unroll
            for (int t = 0; t < 4; ++t) acc[j][d][t] = 0.f;

    // prologue: fill the ring 3 deep
    STAGE(0, 0, true)
    STAGE(1, 1, true)
    STAGE(2, 2, true)

    int s = 0;
    for (int q = 0; q < CT; ++q) {
        // outstanding = stages {q, q+1, q+2} = 12 loads; <=8 => stage(q) done.
        asm volatile("s_waitcnt vmcnt(8)" ::: "memory");
        __builtin_amdgcn_sched_barrier(0);

        const float4 fA = *(const float4*)&lds[g][s][0][4 * l];
        const float4 r0 = *(const float4*)&lds[g][s][1][4 * l];
        const float4 r1 = *(const float4*)&lds[g][s][2][4 * l];
        const float4 r2 = *(const float4*)&lds[g][s][3][4 * l];
        // reads must land in registers before we overwrite slot s
        asm volatile("s_waitcnt lgkmcnt(0)" ::: "memory");
        __builtin_amdgcn_sched_barrier(0);

        // re-stage freed slot with channel q+3 (tail: clamped source -> trash)
        {
            const int  qq   = (q + 3 < CT) ? (q + 3) : (CT - 1);
            const bool real = (q + 3 < CT);
            STAGE(qq, s, real)
        }

        const float fv0 = fA.x, fv1 = fA.y, fv2 = fA.z, fv3 = fA.w;
        COMP_ROW(0, r0)
        COMP_ROW(1, r1)
        COMP_ROW(2, r2)

        s = (s == NSLOT - 1) ? 0 : s + 1;
    }

    const float sc = 1.0f / 128.0f;
#pragma unroll
    for (int j = 0; j < 3; ++j) {
        const int k = (3 * g + j) * 9;
#pragma unroll
        for (int d = 0; d < 9; ++d) {
            float* op = out + ((size_t)(b * NK + k + d) * HH + i0) * WW + 4 * l;
            *(float4*)op = make_float4(acc[j][d][0] * sc, acc[j][d][1] * sc,
                                       acc[j][d][2] * sc, acc[j][d][3] * sc);
        }
    }
}

extern "C" void kernel_launch(void* const* d_in, const int* in_sizes, int n_in,
                              void* d_out, int out_size, void* d_ws, size_t ws_size,
                              hipStream_t stream) {
    const float* f1 = (const float*)d_in[0];
    const float* f2 = (const float*)d_in[1];
    float* out = (float*)d_out;
    dim3 grid(1024);       // one block per (b, i0); swizzled so XCD = batch
    dim3 block(192);       // 3 waves, 3 di each; wave-private LDS ring, no barriers
    hipLaunchKernelGGL(corr_kernel, grid, block, 0, stream, f1, f2, out);
}